// Round 7
// baseline (339.932 us; speedup 1.0000x reference)
//
#include <hip/hip_runtime.h>
#include <stdint.h>
#include <math.h>

// ---------------------------------------------------------------------------
// FlashNeoxAttention: qkv = h@Wqkv+b ; rotary(q,k) ; causal flash attn ; @Wd+b
// T=4096 (B=4 x S=1024), H=16 heads x D=128, ROT=16 (first 32 dims rotated)
// R10 = R9's counted-gate pipeline + UNIT-ALIGNED phase reads (fixes R9 race).
//   R9 bug: QLDB row = wn*96+NH*32 -> waves 2/3 read B1/B2 in phase 1, which
//   the gates hadn't retired yet. Now phase NH reads ONLY unit NH:
//     wave wn owns cols {NH*128 + wn*32 + nf*16 + l15}, acc[mi][NH*2+nf].
//   Calendar (verified T=0,1,steady,30,31; gates match reads exactly):
//     p1(T): read A(T),B0(T); stage B2(T+1)->nb ; gate vmcnt(10) -> B1(T)
//     p2(T): read B1(T)     ; stage A,B0(T+2)->cur; gate vmcnt(12) -> B2(T)
//     p3(T): read B2(T)     ; stage B1(T+2)->cur ; gate vmcnt(10) -> A,B0(T+1)
//   Tail 30/31: 8/4 then 2/0/none. Epilogue re-indexed (rotary = wn==0 pair).
//   gemm_out / attn / aux unchanged from R8.
// ---------------------------------------------------------------------------

typedef __attribute__((ext_vector_type(8))) short short8;   // 8 x bf16 (4 VGPR)
typedef __attribute__((ext_vector_type(4))) float f32x4;    // MFMA C/D frag

__device__ __forceinline__ unsigned short f2b(float f) {
  union { float f; unsigned int i; } x; x.f = f;
  unsigned int r = x.i + 0x7FFFu + ((x.i >> 16) & 1u);  // round-nearest-even
  return (unsigned short)(r >> 16);
}

#define GAS(p) ((const __attribute__((address_space(1))) void*)(p))
#define LAS(p) ((__attribute__((address_space(3))) void*)(p))

// ---------------------------------------------------------------------------
// f32 -> bf16 convert, 8 elems/thread.
// ---------------------------------------------------------------------------
__global__ __launch_bounds__(256) void convert_kernel(
    const float* __restrict__ src, unsigned short* __restrict__ dst) {
  const size_t base = ((size_t)blockIdx.x * 256 + threadIdx.x) * 8;
  float4 v0 = *(const float4*)&src[base];
  float4 v1 = *(const float4*)&src[base + 4];
  unsigned short t8[8] = {f2b(v0.x), f2b(v0.y), f2b(v0.z), f2b(v0.w),
                          f2b(v1.x), f2b(v1.y), f2b(v1.z), f2b(v1.w)};
  *(uint4*)&dst[base] = *(uint4*)t8;
}

// ---------------------------------------------------------------------------
// Transpose+convert W f32 [K][N] -> WT bf16 [N][K], 64x64 tiles, padded LDS.
// ---------------------------------------------------------------------------
__global__ __launch_bounds__(256) void transpose_convert_kernel(
    const float* __restrict__ src, unsigned short* __restrict__ dst,
    const int K, const int N) {
  __shared__ __align__(16) unsigned short tile[64][72];  // +8 pad
  const int n0 = blockIdx.x * 64, k0 = blockIdx.y * 64;
  const int tid = threadIdx.x;
#pragma unroll
  for (int p = 0; p < 2; ++p) {
    const int idx = p * 256 + tid;
    const int r = idx >> 3, c8 = idx & 7;
    const float* sp = &src[(size_t)(k0 + r) * N + n0 + c8 * 8];
    float4 v0 = *(const float4*)sp;
    float4 v1 = *(const float4*)(sp + 4);
    unsigned short t8[8] = {f2b(v0.x), f2b(v0.y), f2b(v0.z), f2b(v0.w),
                            f2b(v1.x), f2b(v1.y), f2b(v1.z), f2b(v1.w)};
    *(uint4*)&tile[r][c8 * 8] = *(uint4*)t8;
  }
  __syncthreads();
#pragma unroll
  for (int p = 0; p < 2; ++p) {
    const int idx = p * 256 + tid;
    const int r = idx >> 3, c8 = idx & 7;
    unsigned short out[8];
#pragma unroll
    for (int j = 0; j < 8; ++j) out[j] = tile[c8 * 8 + j][r];
    *(uint4*)&dst[(size_t)(n0 + r) * K + k0 + c8 * 8] = *(uint4*)out;
  }
}

// ---------------------------------------------------------------------------
// gemm_qkv: 128(M) x 384(N) tile, BK=64, 8 waves (2Mx4N), 3 phases/K-tile,
// grid 32x16 = 512 blocks = 2 exact rounds at 1 block/CU (128 KiB LDS).
// Phase NH computes output col-block NH (128 cols, wave wn owns 32 of them)
// and reads ONLY B-unit NH. Units (2 loads/thread each): A, B0, B1, B2.
// LDS elems: A: buf*8192; B: 16384 + buf*24576 + u*8192.
// ---------------------------------------------------------------------------

#define QSTAGE(SRC, R0, KT, LDSOFF)                                           \
  do {                                                                        \
    _Pragma("unroll") for (int p_ = 0; p_ < 2; ++p_) {                        \
      const int cb_ = w * 2 + p_;                                             \
      __builtin_amdgcn_global_load_lds(                                       \
          GAS((SRC) + (size_t)((R0) + cb_ * 8 + rl) * 2048 + (KT) + cg * 8),  \
          LAS(smem + (LDSOFF) + cb_ * 512), 16, 0, 0);                        \
    }                                                                         \
  } while (0)

#define QLDA                                                                  \
  do {                                                                        \
    _Pragma("unroll") for (int mf_ = 0; mf_ < 4; ++mf_) {                     \
      const int r_ = wm * 64 + mf_ * 16 + l15;                                \
      const unsigned short* rp_ = smem + abo + r_ * 64;                       \
      _Pragma("unroll") for (int ks_ = 0; ks_ < 2; ++ks_)                     \
        af[mf_][ks_] = *(const short8*)&rp_[((ks_ * 4 + g) ^ (r_ & 7)) * 8];  \
    }                                                                         \
  } while (0)

// phase NH reads only B-unit NH: rows NH*128 + wn*32 + nf*16 + l15
#define QLDB(NH)                                                              \
  do {                                                                        \
    _Pragma("unroll") for (int nf_ = 0; nf_ < 2; ++nf_) {                     \
      const int r_ = (NH) * 128 + wn * 32 + nf_ * 16 + l15;                   \
      const unsigned short* rp_ = smem + 16384 + bbo + r_ * 64;               \
      _Pragma("unroll") for (int ks_ = 0; ks_ < 2; ++ks_)                     \
        bfr[nf_][ks_] = *(const short8*)&rp_[((ks_ * 4 + g) ^ (r_ & 7)) * 8]; \
    }                                                                         \
  } while (0)

#define QMMA(NH)                                                              \
  do {                                                                        \
    __builtin_amdgcn_s_setprio(1);                                            \
    _Pragma("unroll") for (int mf_ = 0; mf_ < 4; ++mf_)                       \
    _Pragma("unroll") for (int nf_ = 0; nf_ < 2; ++nf_)                       \
    _Pragma("unroll") for (int ks_ = 0; ks_ < 2; ++ks_)                       \
      acc[mf_][(NH) * 2 + nf_] = __builtin_amdgcn_mfma_f32_16x16x32_bf16(     \
          af[mf_][ks_], bfr[nf_][ks_], acc[mf_][(NH) * 2 + nf_], 0, 0, 0);    \
    __builtin_amdgcn_s_setprio(0);                                            \
    __builtin_amdgcn_sched_barrier(0);                                        \
  } while (0)

__global__ __launch_bounds__(512, 2) void gemm_qkv_kernel(
    const unsigned short* __restrict__ A, const unsigned short* __restrict__ BT,
    const float* __restrict__ bias,
    const float* __restrict__ cosp, const float* __restrict__ sinp,
    unsigned short* __restrict__ q_ws, unsigned short* __restrict__ k_ws,
    unsigned short* __restrict__ vT_ws) {
  extern __shared__ unsigned short smem[];  // 65536 elems = 128 KiB
  const int NT = 32;

  const int tid = threadIdx.x;
  const int lane = tid & 63;
  const int w = tid >> 6;            // wave 0..7
  const int wm = w >> 2, wn = w & 3; // 2M x 4N
  const int l15 = lane & 15, g = lane >> 4;
  const int rl = lane >> 3;                // staging: row within 8-row chunk
  const int cg = (lane & 7) ^ rl;          // pre-swizzled global 16B-chunk

  // bijective XCD swizzle (512 % 8 == 0)
  const int nbx = gridDim.x;               // 16 (n tiles)
  const int cpx = (nbx * gridDim.y) >> 3;
  const int orig = blockIdx.y * nbx + blockIdx.x;
  const int wgid = (orig & 7) * cpx + (orig >> 3);
  const int bx = wgid % nbx, by = wgid / nbx;
  const int m0 = by * 128, n0 = bx * 384;

  f32x4 acc[4][6];
#pragma unroll
  for (int i = 0; i < 4; ++i)
#pragma unroll
    for (int j = 0; j < 6; ++j) acc[i][j] = (f32x4){0.f, 0.f, 0.f, 0.f};

  // prologue: stage tile0 (A,B0,B1,B2 -> buf0) + A,B0,B1(1) -> buf1;
  // gate retires tile0 (leave 6 outstanding); barrier.
  QSTAGE(A, m0, 0, 0);            // A(0)
  QSTAGE(BT, n0, 0, 16384);       // B0(0)
  QSTAGE(BT, n0 + 128, 0, 24576); // B1(0)
  QSTAGE(BT, n0 + 256, 0, 32768); // B2(0)
  QSTAGE(A, m0, 64, 8192);                  // A(1)
  QSTAGE(BT, n0, 64, 16384 + 24576);        // B0(1)
  QSTAGE(BT, n0 + 128, 64, 24576 + 24576);  // B1(1)
  asm volatile("s_waitcnt vmcnt(6)" ::: "memory");  // tile0 resident
  __builtin_amdgcn_s_barrier();

  short8 af[4][2], bfr[2][2];

  for (int T = 0; T < NT; ++T) {
    const int buf = T & 1, nb = buf ^ 1;
    const int abo = buf * 8192;
    const int bbo = buf * 24576;
    const int nbbo = nb * 24576;
    const int ktn = (T + 1) << 6;
    const int ktn2 = (T + 2) << 6;

    // ---- p1: read A(T),B0(T); stage B2(T+1)->nb; gate -> B1(T) ----
    QLDA;
    QLDB(0);
    if (T + 1 < NT) QSTAGE(BT, n0 + 256, ktn, 32768 + nbbo);   // B2(T+1)
    if (T >= 1 && T <= 30) {
      asm volatile("s_waitcnt vmcnt(10)" ::: "memory");
    } else if (T == 31) {
      asm volatile("s_waitcnt vmcnt(2)" ::: "memory");
    }
    __builtin_amdgcn_s_barrier();
    asm volatile("s_waitcnt lgkmcnt(0)" ::: "memory");
    __builtin_amdgcn_sched_barrier(0);
    QMMA(0);
    __builtin_amdgcn_s_barrier();

    // ---- p2: read B1(T); stage A,B0(T+2)->cur; gate -> B2(T) ----
    QLDB(1);
    if (T + 2 < NT) {
      QSTAGE(A, m0, ktn2, abo);             // A(T+2) -> current buf
      QSTAGE(BT, n0, ktn2, 16384 + bbo);    // B0(T+2) -> current buf
    }
    if (T >= 1 && T <= 29) {
      asm volatile("s_waitcnt vmcnt(12)" ::: "memory");
    } else if (T == 30) {
      asm volatile("s_waitcnt vmcnt(8)" ::: "memory");
    } else if (T == 31) {
      asm volatile("s_waitcnt vmcnt(0)" ::: "memory");
    }
    __builtin_amdgcn_s_barrier();
    asm volatile("s_waitcnt lgkmcnt(0)" ::: "memory");
    __builtin_amdgcn_sched_barrier(0);
    QMMA(1);
    __builtin_amdgcn_s_barrier();

    // ---- p3: read B2(T); stage B1(T+2)->cur; gate -> A,B0(T+1) ----
    QLDB(2);
    if (T + 2 < NT) QSTAGE(BT, n0 + 128, ktn2, 24576 + bbo);   // B1(T+2)
    if (T <= 29) {
      asm volatile("s_waitcnt vmcnt(10)" ::: "memory");
    } else if (T == 30) {
      asm volatile("s_waitcnt vmcnt(4)" ::: "memory");
    }  // T==31: nothing outstanding
    __builtin_amdgcn_s_barrier();
    asm volatile("s_waitcnt lgkmcnt(0)" ::: "memory");
    __builtin_amdgcn_sched_barrier(0);
    QMMA(2);
    __builtin_amdgcn_s_barrier();
  }

  // ---- epilogue. col for acc[mi][NH*2+nf] = n0 + NH*128 + wn*32 + nf*16+l15
  float bv[6];
#pragma unroll
  for (int j = 0; j < 6; ++j)
    bv[j] = bias[n0 + (j >> 1) * 128 + wn * 32 + (j & 1) * 16 + l15];
#pragma unroll
  for (int mi = 0; mi < 4; ++mi)
#pragma unroll
    for (int j = 0; j < 6; ++j)
#pragma unroll
      for (int jj = 0; jj < 4; ++jj) acc[mi][j][jj] += bv[j];

  // ---- rotary: head-local dims 0..31 = cols (NH,*,wn==0,nf 0|1) ----
  if (wn == 0) {
#pragma unroll
    for (int NH = 0; NH < 3; ++NH) {
      const int whichj = (n0 + NH * 128) >> 11;   // 0=q 1=k 2=v
      if (whichj < 2) {
#pragma unroll
        for (int mi = 0; mi < 4; ++mi)
#pragma unroll
          for (int jj = 0; jj < 4; ++jj) {
            const int t = m0 + wm * 64 + mi * 16 + g * 4 + jj;
            const float c = cosp[t * 16 + l15];
            const float s = sinp[t * 16 + l15];
            const float a1 = acc[mi][NH * 2][jj], a2 = acc[mi][NH * 2 + 1][jj];
            acc[mi][NH * 2][jj] = a1 * c - a2 * s;
            acc[mi][NH * 2 + 1][jj] = a1 * s + a2 * c;
          }
      }
    }
  }

  // ---- write C into 3 per-head LDS sub-tiles [128][136] (v transposed) ----
  const int b = m0 >> 10, s0v = m0 & 1023;
#pragma unroll
  for (int mi = 0; mi < 4; ++mi)
#pragma unroll
    for (int j = 0; j < 6; ++j)
#pragma unroll
      for (int jj = 0; jj < 4; ++jj) {
        const int NH = j >> 1;
        const int r = wm * 64 + mi * 16 + g * 4 + jj;    // token-local 0..127
        const int lc = wn * 32 + (j & 1) * 16 + l15;     // head-local 0..127
        const int whichj = (n0 + NH * 128) >> 11;
        const unsigned short hv = f2b(acc[mi][j][jj]);
        if (whichj < 2) smem[NH * 17408 + r * 136 + lc] = hv;
        else            smem[NH * 17408 + lc * 136 + r] = hv;
      }
  __syncthreads();

  // ---- flush sub-tiles, per-block q/k/v routing ----
#pragma unroll
  for (int jb = 0; jb < 3; ++jb) {
    const int gcb = n0 + jb * 128;
    const int whichj = gcb >> 11;
    const int head = (gcb >> 7) & 15;
#pragma unroll
    for (int p4 = 0; p4 < 4; ++p4) {
      const int idx = p4 * 512 + tid;
      const int rr = idx >> 4, c8 = idx & 15;
      uint4 v = *(const uint4*)&smem[jb * 17408 + rr * 136 + c8 * 8];
      unsigned short* dp;
      if (whichj == 0)
        dp = q_ws + ((size_t)(b * 16 + head) * 1024 + s0v + rr) * 128 + c8 * 8;
      else if (whichj == 1)
        dp = k_ws + ((size_t)(b * 16 + head) * 1024 + s0v + rr) * 128 + c8 * 8;
      else  // v: sub-tile row rr = head-dim d, cols = local tokens
        dp = vT_ws + ((size_t)(b * 16 + head) * 128 + rr) * 1024 + s0v + c8 * 8;
      *(uint4*)dp = v;
    }
  }
}

// ---------------------------------------------------------------------------
// gemm_out: C[4096][2048] f32 = A @ WdT^T + bias. Tile 128(M) x 256(N), BK=64,
// grid 8x32 = 256 blocks (exactly one full dispatch round). 8 waves (2Mx4N),
// wave out 64x64, 2 phases/K-tile (nf01 / nf23), 16 MFMA each. (R5 form,
// calendar audited race-free: gate is always a full phase ahead of reads.)
// ---------------------------------------------------------------------------

#define M1_STG(SRC, R0, KT, LB)                                               \
  __builtin_amdgcn_global_load_lds(                                           \
      GAS((SRC) + (size_t)((R0) + w * 8 + rl) * 2048 + (KT) + cg * 8),        \
      LAS(smem + (LB) + w * 512), 16, 0, 0)

#define M1_LDA                                                                \
  do {                                                                        \
    _Pragma("unroll") for (int mf_ = 0; mf_ < 4; ++mf_) {                     \
      const int r_ = wm * 64 + mf_ * 16 + l15;                                \
      const unsigned short* rp_ = smem + abo + r_ * 64;                       \
      _Pragma("unroll") for (int ks_ = 0; ks_ < 2; ++ks_)                     \
        af[mf_][ks_] = *(const short8*)&rp_[((ks_ * 4 + g) ^ (r_ & 7)) * 8];  \
    }                                                                         \
  } while (0)

#define M1_LDB(NH)                                                            \
  do {                                                                        \
    _Pragma("unroll") for (int nf_ = 0; nf_ < 2; ++nf_) {                     \
      const int r_ = wn * 64 + (NH) * 32 + nf_ * 16 + l15;                    \
      const unsigned short* rp_ = smem + bbo + r_ * 64;                       \
      _Pragma("unroll") for (int ks_ = 0; ks_ < 2; ++ks_)                     \
        bfr[nf_][ks_] = *(const short8*)&rp_[((ks_ * 4 + g) ^ (r_ & 7)) * 8]; \
    }                                                                         \
  } while (0)

#define M1_MMA(NH)                                                            \
  do {                                                                        \
    __builtin_amdgcn_s_setprio(1);                                            \
    _Pragma("unroll") for (int mf_ = 0; mf_ < 4; ++mf_)                       \
    _Pragma("unroll") for (int nf_ = 0; nf_ < 2; ++nf_)                       \
    _Pragma("unroll") for (int ks_ = 0; ks_ < 2; ++ks_)                       \
      acc[mf_][(NH) * 2 + nf_] = __builtin_amdgcn_mfma_f32_16x16x32_bf16(     \
          af[mf_][ks_], bfr[nf_][ks_], acc[mf_][(NH) * 2 + nf_], 0, 0, 0);    \
    __builtin_amdgcn_s_setprio(0);                                            \
    __builtin_amdgcn_sched_barrier(0);                                        \
  } while (0)

__global__ __launch_bounds__(512, 2) void gemm_out_kernel(
    const unsigned short* __restrict__ A, const unsigned short* __restrict__ BT,
    const float* __restrict__ bias, float* __restrict__ outp) {
  extern __shared__ unsigned short smem[];  // 49152 elems = 96 KiB
  const int NT = 32;

  const int tid = threadIdx.x;
  const int lane = tid & 63;
  const int w = tid >> 6;
  const int wm = w >> 2, wn = w & 3;   // 2M x 4N, wave out 64x64
  const int l15 = lane & 15, g = lane >> 4;
  const int rl = lane >> 3;
  const int cg = (lane & 7) ^ rl;

  // bijective XCD swizzle (256 % 8 == 0)
  const int nbx = gridDim.x;
  const int cpx = (nbx * gridDim.y) >> 3;
  const int orig = blockIdx.y * nbx + blockIdx.x;
  const int wgid = (orig & 7) * cpx + (orig >> 3);
  const int bx = wgid % nbx, by = wgid / nbx;
  const int m0 = by * 128, n0 = bx * 256;

  f32x4 acc[4][4];
#pragma unroll
  for (int i = 0; i < 4; ++i)
#pragma unroll
    for (int j = 0; j < 4; ++j) acc[i][j] = (f32x4){0.f, 0.f, 0.f, 0.f};

  // prologue: A01(0), BQ0..3(0), A01(1); gate retires tile0 (6 loads)
  M1_STG(A, m0, 0, 0);
  M1_STG(A, m0 + 64, 0, 4096);
  M1_STG(BT, n0, 0, 16384);
  M1_STG(BT, n0 + 64, 0, 16384 + 4096);
  M1_STG(BT, n0 + 128, 0, 16384 + 8192);
  M1_STG(BT, n0 + 192, 0, 16384 + 12288);
  M1_STG(A, m0, 64, 8192);
  M1_STG(A, m0 + 64, 64, 12288);
  asm volatile("s_waitcnt vmcnt(2)" ::: "memory");
  __builtin_amdgcn_s_barrier();

  short8 af[4][2], bfr[2][2];

  for (int T = 0; T < NT; ++T) {
    const int buf = T & 1, nb = buf ^ 1;
    const int abo = buf * 8192;
    const int bbo = 16384 + buf * 16384;
    const int ktn = (T + 1) << 6;
    const int ktn2 = (T + 2) << 6;
    const bool pf1 = (T + 1 < NT), pf2 = (T + 2 < NT);

    // ---- p1: nf 0-1 ----
    M1_LDA;
    M1_LDB(0);
    if (pf1) {
      M1_STG(BT, n0, ktn, 16384 + nb * 16384);
      M1_STG(BT, n0 + 64, ktn, 16384 + nb * 16384 + 4096);
      M1_STG(BT, n0 + 128, ktn, 16384 + nb * 16384 + 8192);
      M1_STG(BT, n0 + 192, ktn, 16384 + nb * 16384 + 12288);
    }
    __builtin_amdgcn_s_barrier();
    asm volatile("s_waitcnt lgkmcnt(0)" ::: "memory");
    __builtin_amdgcn_sched_barrier(0);
    M1_MMA(0);
    __builtin_amdgcn_s_barrier();

    // ---- p2: nf 2-3 ----
    M1_LDB(1);
    if (pf2) {
      M1_STG(A, m0, ktn2, abo);          // A01(T+2) -> current buf (rolling)
      M1_STG(A, m0 + 64, ktn2, abo + 4096);
      asm volatile("s_waitcnt vmcnt(2)" ::: "memory");  // retire tile T+1
    } else if (pf1) {
      asm volatile("s_waitcnt vmcnt(0)" ::: "memory");
    }
    __builtin_amdgcn_s_barrier();
    asm volatile("s_waitcnt lgkmcnt(0)" ::: "memory");
    __builtin_amdgcn_sched_barrier(0);
    M1_MMA(1);
    __builtin_amdgcn_s_barrier();
  }

  // ---- epilogue: bias + f32 store ----
  float bv[4];
#pragma unroll
  for (int nf = 0; nf < 4; ++nf) bv[nf] = bias[n0 + wn * 64 + nf * 16 + l15];
#pragma unroll
  for (int mi = 0; mi < 4; ++mi)
#pragma unroll
    for (int nf = 0; nf < 4; ++nf)
#pragma unroll
      for (int jj = 0; jj < 4; ++jj) {
        const int r = wm * 64 + mi * 16 + g * 4 + jj;
        const int c = wn * 64 + nf * 16 + l15;
        outp[(size_t)(m0 + r) * 2048 + n0 + c] = acc[mi][nf][jj] + bv[nf];
      }
}

// ---------------------------------------------------------------------------
// Causal flash attention (R3 + T5 setprio). Block = (q-tile 64, bh), 4 waves.
// ---------------------------------------------------------------------------
__global__ __launch_bounds__(256) void attn_kernel(
    const unsigned short* __restrict__ q_ws, const unsigned short* __restrict__ k_ws,
    const unsigned short* __restrict__ vT_ws, unsigned short* __restrict__ attn_ws) {
  __shared__ __align__(16) unsigned short Ksl[2][8192];  // [kv 64][d 128] swizzled
  __shared__ __align__(16) unsigned short Vsl[2][8192];  // [d 128][kv 64] swizzled
  __shared__ __align__(16) unsigned short Psl[64 * 72];  // [q 64][kv 64+8]

  const int tid = threadIdx.x;
  const int lane = tid & 63;
  const int w = tid >> 6;
  const int l15 = lane & 15, g = lane >> 4;

  const int lid = blockIdx.x;                 // 0..1023
  const int bh  = (lid & 7) + 8 * ((lid >> 3) & 7);   // same bh -> same XCD
  const int qt  = 15 - (lid >> 6);            // big q-tiles dispatch first
  const int q0  = qt * 64;
  const size_t qkb = (size_t)bh * 131072;     // 1024*128
  const unsigned short* kg = k_ws + qkb;
  const unsigned short* vg = vT_ws + qkb;

  short8 qf[4];
#pragma unroll
  for (int ks = 0; ks < 4; ++ks)
    qf[ks] = *(const short8*)&q_ws[qkb + (size_t)(q0 + w * 16 + l15) * 128 + ks * 32 + g * 8];

  f32x4 o[8];
#pragma unroll
  for (int j = 0; j < 8; ++j) o[j] = (f32x4){0.f, 0.f, 0.f, 0.f};
  float lsum[4] = {0.f, 0.f, 0.f, 0.f};

  const float CS = 0.08838834764831845f * 1.4426950408889634f;  // scale*log2e
  const int ntiles = qt + 1;

#pragma unroll
  for (int p = 0; p < 4; ++p) {
    const int base = (w * 4 + p) * 64;        // chunk base (wave-uniform)
    {
      const int L = base + lane, r = L >> 4, s = L & 15;
      const int c = (s & 8) | ((s ^ r) & 7);
      __builtin_amdgcn_global_load_lds(GAS(kg + r * 128 + c * 8),
                                       LAS(&Ksl[0][base * 8]), 16, 0, 0);
    }
    {
      const int L = base + lane, r = L >> 3, s = L & 7;
      const int c = (s ^ r) & 7;
      __builtin_amdgcn_global_load_lds(GAS(vg + (size_t)r * 1024 + c * 8),
                                       LAS(&Vsl[0][base * 8]), 16, 0, 0);
    }
  }

  int buf = 0;
  for (int jt = 0; jt < ntiles; ++jt) {
    __syncthreads();   // tile jt staged; previous buf's readers done

    if (jt + 1 < ntiles) {  // async prefetch jt+1 -> other buf
      const unsigned short* kb = kg + (size_t)(jt + 1) * 8192;
      const unsigned short* vb = vg + (jt + 1) * 64;
      const int nb = buf ^ 1;
#pragma unroll
      for (int p = 0; p < 4; ++p) {
        const int base = (w * 4 + p) * 64;
        {
          const int L = base + lane, r = L >> 4, s = L & 15;
          const int c = (s & 8) | ((s ^ r) & 7);
          __builtin_amdgcn_global_load_lds(GAS(kb + r * 128 + c * 8),
                                           LAS(&Ksl[nb][base * 8]), 16, 0, 0);
        }
        {
          const int L = base + lane, r = L >> 3, s = L & 7;
          const int c = (s ^ r) & 7;
          __builtin_amdgcn_global_load_lds(GAS(vb + (size_t)r * 1024 + c * 8),
                                           LAS(&Vsl[nb][base * 8]), 16, 0, 0);
        }
      }
    }

    f32x4 s[4];
#pragma unroll
    for (int nf = 0; nf < 4; ++nf) s[nf] = (f32x4){0.f, 0.f, 0.f, 0.f};
    __builtin_amdgcn_s_setprio(1);
#pragma unroll
    for (int nf = 0; nf < 4; ++nf) {
      const int r = nf * 16 + l15;
#pragma unroll
      for (int ks = 0; ks < 4; ++ks) {
        const int c = ks * 4 + g;
        const int sl = (c & 8) | ((c ^ r) & 7);
        short8 bfrk = *(const short8*)&Ksl[buf][r * 128 + sl * 8];
        s[nf] = __builtin_amdgcn_mfma_f32_16x16x32_bf16(qf[ks], bfrk, s[nf], 0, 0, 0);
      }
    }
    __builtin_amdgcn_s_setprio(0);

    const bool diag = (jt == ntiles - 1);
#pragma unroll
    for (int jj = 0; jj < 4; ++jj) {
      float pv[4];
      if (diag) {
        const int rloc = w * 16 + g * 4 + jj;   // kv0 == q0 on diagonal
#pragma unroll
        for (int nf = 0; nf < 4; ++nf)
          pv[nf] = (nf * 16 + l15 > rloc) ? 0.f
                 : __builtin_amdgcn_exp2f(s[nf][jj] * CS);
      } else {
#pragma unroll
        for (int nf = 0; nf < 4; ++nf)
          pv[nf] = __builtin_amdgcn_exp2f(s[nf][jj] * CS);
      }
      lsum[jj] += (pv[0] + pv[1]) + (pv[2] + pv[3]);
#pragma unroll
      for (int nf = 0; nf < 4; ++nf)
        Psl[(w * 16 + g * 4 + jj) * 72 + nf * 16 + l15] = f2b(pv[nf]);
    }

    __builtin_amdgcn_s_setprio(1);
#pragma unroll
    for (int ks = 0; ks < 2; ++ks) {
      short8 a0 = *(const short8*)&Psl[(w * 16 + l15) * 72 + ks * 32 + g * 8];
#pragma unroll
      for (int nd = 0; nd < 8; ++nd) {
        const int r = nd * 16 + l15;
        const int c = ks * 4 + g;
        const int sl = (c ^ r) & 7;
        short8 bfrv = *(const short8*)&Vsl[buf][r * 64 + sl * 8];
        o[nd] = __builtin_amdgcn_mfma_f32_16x16x32_bf16(a0, bfrv, o[nd], 0, 0, 0);
      }
    }
    __builtin_amdgcn_s_setprio(0);
    buf ^= 1;
  }

#pragma unroll
  for (int jj = 0; jj < 4; ++jj) {
    float rs = lsum[jj];
    rs += __shfl_xor(rs, 1);
    rs += __shfl_xor(rs, 2);
    rs += __shfl_xor(rs, 4);
    rs += __shfl_xor(rs, 8);
    const float inv = 1.f / rs;
    const int t = (bh >> 4) * 1024 + q0 + w * 16 + g * 4 + jj;
    unsigned short* dst = attn_ws + (size_t)t * 2048 + (bh & 15) * 128;
#pragma unroll
    for (int nd = 0; nd < 8; ++nd)
      dst[nd * 16 + l15] = f2b(o[nd][jj] * inv);
  }
}

// ---------------------------------------------------------------------------
extern "C" void kernel_launch(void* const* d_in, const int* in_sizes, int n_in,
                              void* d_out, int out_size, void* d_ws, size_t ws_size,
                              hipStream_t stream) {
  const float* hidden = (const float*)d_in[0];
  const float* cosp   = (const float*)d_in[1];
  const float* sinp   = (const float*)d_in[2];
  const float* Wqkv   = (const float*)d_in[3];
  const float* bqkv   = (const float*)d_in[4];
  const float* Wd     = (const float*)d_in[5];
  const float* bd     = (const float*)d_in[6];

  // ws layout (bf16 elems), aliased:
  //   [0, 8.39M)       hidden_bf  -> (dead after G0) attn_bf
  //   [8.39M, 20.97M)  WqkvT      -> (dead after G0) WdT
  //   [20.97M, ...)    q_ws, k_ws, vT_ws (8.39M each)
  unsigned short* ws        = (unsigned short*)d_ws;
  unsigned short* hidden_bf = ws;
  unsigned short* attn_bf   = ws;
  unsigned short* WqkvT     = ws + 8388608;
  unsigned short* WdT       = ws + 8388608;
  unsigned short* q_ws      = ws + 20971520;
  unsigned short* k_ws      = q_ws + 8388608;
  unsigned short* vT_ws     = k_ws + 8388608;

  static bool attr_inited = false;
  if (!attr_inited) {
    hipFuncSetAttribute(reinterpret_cast<const void*>(gemm_qkv_kernel),
                        hipFuncAttributeMaxDynamicSharedMemorySize, 131072);
    hipFuncSetAttribute(reinterpret_cast<const void*>(gemm_out_kernel),
                        hipFuncAttributeMaxDynamicSharedMemorySize, 98304);
    attr_inited = true;
  }

  convert_kernel<<<4096, 256, 0, stream>>>(hidden, hidden_bf);
  transpose_convert_kernel<<<dim3(96, 32), 256, 0, stream>>>(Wqkv, WqkvT, 2048, 6144);
  gemm_qkv_kernel<<<dim3(16, 32), 512, 131072, stream>>>(
      hidden_bf, WqkvT, bqkv, cosp, sinp, q_ws, k_ws, vT_ws);
  attn_kernel<<<1024, 256, 0, stream>>>(q_ws, k_ws, vT_ws, attn_bf);
  transpose_convert_kernel<<<dim3(32, 32), 256, 0, stream>>>(Wd, WdT, 2048, 2048);
  gemm_out_kernel<<<dim3(8, 32), 512, 98304, stream>>>(
      attn_bf, WdT, bd, (float*)d_out);
}